// Round 11
// baseline (191.005 us; speedup 1.0000x reference)
//
#include <hip/hip_runtime.h>

#define D 4096

typedef float fx4 __attribute__((ext_vector_type(4)));

// ws layout (floats). memset zeroes [0, 4D+16) every call.
//   [0,D)   CS0 colsum0 (global atomics)
//   [D,2D)  CS1 colsum1 (global atomics)
//   [2D,3D) RS1 rowsum1 (one atomicAdd per row, from applyT1 blocks)
//   [3D,4D) RS2 rowsum2 (one atomicAdd per row, from applyT2 blocks)
//   4D..    CNTA/CNTB/CNTC completion counters (uint)
//   4D+16.. M0,M1,M2,M3 messages [4][D]; S2S scalar
#define CS0 0
#define CS1 D
#define RS1 (2 * D)
#define RS2 (3 * D)
#define CNTA (4 * D)
#define CNTB (4 * D + 1)
#define CNTC (4 * D + 2)
#define M0O (4 * D + 16)
#define M1O (5 * D + 16)
#define M2O (6 * D + 16)
#define M3O (7 * D + 16)
#define S2S (8 * D + 16)

__device__ __forceinline__ float block_sum_256(float v, float* red) {
    #pragma unroll
    for (int o = 32; o > 0; o >>= 1) v += __shfl_down(v, o);
    int lane = threadIdx.x & 63, wid = threadIdx.x >> 6;
    if (lane == 0) red[wid] = v;
    __syncthreads();
    if (threadIdx.x == 0) red[0] = (red[0] + red[1]) + (red[2] + red[3]);
    __syncthreads();
    float r = red[0];
    __syncthreads();
    return r;
}

// ---------------- K1: colsums of t0,t1 + tail msgsA ----------------
// 512 blocks x 256 (R3-proven geometry). Last block computes m0, S0, m1.
__global__ void __launch_bounds__(256) colsum_msgsA_kernel(
        const float* __restrict__ t0, const float* __restrict__ t1,
        float* __restrict__ ws,
        const int* __restrict__ op0, const int* __restrict__ op1) {
    int b = blockIdx.x, tid = threadIdx.x;
    {
        const float* A = (b < 256) ? t0 : t1;
        float* outp = ws + ((b < 256) ? CS0 : CS1);
        int lb = b & 255;
        int c4 = (lb & 3) * 256 + tid;             // fx4-column 0..1023
        int r0 = (lb >> 2) * 64;                   // 64-row stripe
        const fx4* A4 = (const fx4*)A;
        fx4 s = (fx4){0.f, 0.f, 0.f, 0.f};
        #pragma unroll 8
        for (int r = 0; r < 64; ++r)
            s += A4[(size_t)(r0 + r) * (D / 4) + c4];
        atomicAdd(&outp[c4 * 4 + 0], s.x);
        atomicAdd(&outp[c4 * 4 + 1], s.y);
        atomicAdd(&outp[c4 * 4 + 2], s.z);
        atomicAdd(&outp[c4 * 4 + 3], s.w);
    }
    __syncthreads();   // vmcnt(0) before barrier: this block's atomics are done
    __shared__ unsigned int lastflag;
    if (tid == 0)
        lastflag = (atomicAdd((unsigned int*)(ws + CNTA), 1u) == 511u);
    __syncthreads();
    if (!lastflag) return;
    __threadfence();   // acquire (tail block only; 4 waves)

    // ---- msgsA: m0 = remap(CS0, op0); S0 = sum(m0); m1 = remap(CS1 + S0, op1)
    __shared__ float m0[D], m1[D];
    __shared__ float red[4];
    #pragma unroll
    for (int k = 0; k < 16; ++k) {
        m0[tid + 256 * k] = 0.f; m1[tid + 256 * k] = 0.f;
    }
    __syncthreads();
    #pragma unroll
    for (int c = 0; c < 2; ++c) {
        int sx[8], dx[8]; float g[8];
        #pragma unroll
        for (int j = 0; j < 8; ++j) {
            int i = tid + (c * 8 + j) * 256;
            sx[j] = op0[i]; dx[j] = op0[D + i];
        }
        #pragma unroll
        for (int j = 0; j < 8; ++j) g[j] = ws[CS0 + sx[j]];
        #pragma unroll
        for (int j = 0; j < 8; ++j) atomicAdd(&m0[dx[j]], g[j]);
    }
    __syncthreads();
    float p = 0.f;
    #pragma unroll
    for (int k = 0; k < 16; ++k) p += m0[tid + 256 * k];
    float S0 = block_sum_256(p, red);
    #pragma unroll
    for (int c = 0; c < 2; ++c) {
        int sx[8], dx[8]; float g[8];
        #pragma unroll
        for (int j = 0; j < 8; ++j) {
            int i = tid + (c * 8 + j) * 256;
            sx[j] = op1[i]; dx[j] = op1[D + i];
        }
        #pragma unroll
        for (int j = 0; j < 8; ++j) g[j] = ws[CS1 + sx[j]];
        #pragma unroll
        for (int j = 0; j < 8; ++j) atomicAdd(&m1[dx[j]], g[j] + S0);
    }
    __syncthreads();
    #pragma unroll
    for (int k = 0; k < 16; ++k) {
        ws[M0O + tid + 256 * k] = m0[tid + 256 * k];
        ws[M1O + tid + 256 * k] = m1[tid + 256 * k];
    }
}

// ---------------- K2: applyT2 (+rowsum2) + tail msgsB ----------------
// D blocks x 256; block = one row. out2 = t2 + m1[row]; RS2[row] += rowsum.
__global__ void __launch_bounds__(256) applyT2_msgsB_kernel(
        const float* __restrict__ t2, float* __restrict__ ws,
        float* __restrict__ out2, const int* __restrict__ op2) {
    int row = blockIdx.x, tid = threadIdx.x;
    __shared__ float red[4];
    {
        size_t base = (size_t)row * D;
        const fx4* src = (const fx4*)(t2 + base);
        fx4* dst = (fx4*)(out2 + base);
        float rr = ws[M1O + row];
        fx4 v[4]; float s = 0.f;
        #pragma unroll
        for (int k = 0; k < 4; ++k) {
            v[k] = src[tid + 256 * k];
            s += (v[k].x + v[k].y) + (v[k].z + v[k].w);
        }
        #pragma unroll
        for (int k = 0; k < 4; ++k)
            __builtin_nontemporal_store(v[k] + rr, &dst[tid + 256 * k]);
        #pragma unroll
        for (int o = 32; o > 0; o >>= 1) s += __shfl_down(s, o);
        int lane = tid & 63, wid = tid >> 6;
        if (lane == 0) red[wid] = s;
        __syncthreads();
        if (tid == 0)
            atomicAdd(&ws[RS2 + row], (red[0] + red[1]) + (red[2] + red[3]));
    }
    __syncthreads();   // drain this block's atomic + stores
    __shared__ unsigned int lastflag;
    if (tid == 0)
        lastflag = (atomicAdd((unsigned int*)(ws + CNTB), 1u) == (unsigned)(D - 1));
    __syncthreads();
    if (!lastflag) return;
    __threadfence();   // acquire (tail block only)

    // ---- msgsB: m2 = remap(RS2 + 4095*m1, op2); S2 = sum(m2)
    __shared__ float m2[D];
    #pragma unroll
    for (int k = 0; k < 16; ++k) m2[tid + 256 * k] = 0.f;
    __syncthreads();
    #pragma unroll
    for (int c = 0; c < 2; ++c) {
        int sx[8], dx[8]; float g[8];
        #pragma unroll
        for (int j = 0; j < 8; ++j) {
            int i = tid + (c * 8 + j) * 256;
            sx[j] = op2[i]; dx[j] = op2[D + i];
        }
        #pragma unroll
        for (int j = 0; j < 8; ++j)
            g[j] = ws[RS2 + sx[j]] + 4095.0f * ws[M1O + sx[j]];
        #pragma unroll
        for (int j = 0; j < 8; ++j) atomicAdd(&m2[dx[j]], g[j]);
    }
    __syncthreads();
    float p = 0.f;
    #pragma unroll
    for (int k = 0; k < 16; ++k) p += m2[tid + 256 * k];
    float S2 = block_sum_256(p, red);
    #pragma unroll
    for (int k = 0; k < 16; ++k) ws[M2O + tid + 256 * k] = m2[tid + 256 * k];
    if (tid == 0) ws[S2S] = S2;
}

// ---------------- K3: applyT1 (+rowsum1) + tail msgsC ----------------
// out1 = t1 + m0[row] + m2[col]; RS1[row] += rowsum. Tail computes m3.
__global__ void __launch_bounds__(256) applyT1_msgsC_kernel(
        const float* __restrict__ t1, float* __restrict__ ws,
        float* __restrict__ out1, const int* __restrict__ op3) {
    int row = blockIdx.x, tid = threadIdx.x;
    __shared__ float red[4];
    {
        size_t base = (size_t)row * D;
        const fx4* src = (const fx4*)(t1 + base);
        const fx4* c4 = (const fx4*)(ws + M2O);
        fx4* dst = (fx4*)(out1 + base);
        float rr = ws[M0O + row];
        fx4 v[4], c[4]; float s = 0.f;
        #pragma unroll
        for (int k = 0; k < 4; ++k) {
            v[k] = src[tid + 256 * k];
            c[k] = c4[tid + 256 * k];
            s += (v[k].x + v[k].y) + (v[k].z + v[k].w);
        }
        #pragma unroll
        for (int k = 0; k < 4; ++k)
            __builtin_nontemporal_store(v[k] + c[k] + rr, &dst[tid + 256 * k]);
        #pragma unroll
        for (int o = 32; o > 0; o >>= 1) s += __shfl_down(s, o);
        int lane = tid & 63, wid = tid >> 6;
        if (lane == 0) red[wid] = s;
        __syncthreads();
        if (tid == 0)
            atomicAdd(&ws[RS1 + row], (red[0] + red[1]) + (red[2] + red[3]));
    }
    __syncthreads();
    __shared__ unsigned int lastflag;
    if (tid == 0)
        lastflag = (atomicAdd((unsigned int*)(ws + CNTC), 1u) == (unsigned)(D - 1));
    __syncthreads();
    if (!lastflag) return;
    __threadfence();   // acquire (tail block only)

    // ---- msgsC: m3 = remap(RS1 + 4095*m0 + S2, op3)
    __shared__ float m3[D];
    float S2 = ws[S2S];
    #pragma unroll
    for (int k = 0; k < 16; ++k) m3[tid + 256 * k] = 0.f;
    __syncthreads();
    #pragma unroll
    for (int c = 0; c < 2; ++c) {
        int sx[8], dx[8]; float g[8];
        #pragma unroll
        for (int j = 0; j < 8; ++j) {
            int i = tid + (c * 8 + j) * 256;
            sx[j] = op3[i]; dx[j] = op3[D + i];
        }
        #pragma unroll
        for (int j = 0; j < 8; ++j)
            g[j] = ws[RS1 + sx[j]] + 4095.0f * ws[M0O + sx[j]] + S2;
        #pragma unroll
        for (int j = 0; j < 8; ++j) atomicAdd(&m3[dx[j]], g[j]);
    }
    __syncthreads();
    #pragma unroll
    for (int k = 0; k < 16; ++k) ws[M3O + tid + 256 * k] = m3[tid + 256 * k];
}

// ---------------- K4: applyT0 ----------------
// out0 = t0 + m3[col]
__global__ void __launch_bounds__(256) applyT0_kernel(
        const float* __restrict__ t0, const float* __restrict__ ws,
        float* __restrict__ out0) {
    int row = blockIdx.x;
    size_t base = (size_t)row * D;
    const fx4* src = (const fx4*)(t0 + base);
    const fx4* c4 = (const fx4*)(ws + M3O);
    fx4* dst = (fx4*)(out0 + base);
    #pragma unroll
    for (int k = 0; k < 4; ++k) {
        fx4 r = src[threadIdx.x + 256 * k] + c4[threadIdx.x + 256 * k];
        __builtin_nontemporal_store(r, &dst[threadIdx.x + 256 * k]);
    }
}

extern "C" void kernel_launch(void* const* d_in, const int* in_sizes, int n_in,
                              void* d_out, int out_size, void* d_ws, size_t ws_size,
                              hipStream_t stream) {
    const float* t0 = (const float*)d_in[0];
    const float* t1 = (const float*)d_in[1];
    const float* t2 = (const float*)d_in[2];
    const int* op0 = (const int*)d_in[3];
    const int* op1 = (const int*)d_in[4];
    const int* op2 = (const int*)d_in[5];
    const int* op3 = (const int*)d_in[6];
    float* out = (float*)d_out;
    float* ws = (float*)d_ws;

    // zero CS0, CS1, RS1, RS2, counters (one contiguous region)
    hipMemsetAsync(ws, 0, (4 * D + 16) * sizeof(float), stream);

    colsum_msgsA_kernel<<<512, 256, 0, stream>>>(t0, t1, ws, op0, op1);
    applyT2_msgsB_kernel<<<D, 256, 0, stream>>>(t2, ws, out + 2 * (size_t)D * D, op2);
    applyT1_msgsC_kernel<<<D, 256, 0, stream>>>(t1, ws, out + 1 * (size_t)D * D, op3);
    applyT0_kernel<<<D, 256, 0, stream>>>(t0, ws, out + 0 * (size_t)D * D);
}

// Round 12
// 144.595 us; speedup vs baseline: 1.3210x; 1.3210x over previous
//
#include <hip/hip_runtime.h>

#define D 4096

typedef float fx4 __attribute__((ext_vector_type(4)));
typedef int   ix4 __attribute__((ext_vector_type(4)));

// ws layout (floats):
//   CS0=0 colsum0[D] (atomics; memset)   CS1=D colsum1[D] (atomics; memset)
//   RS1=2D rowsum1[D] (by applyT1)       RS2=3D rowsum2[D] (by applyT2)
//   M0=4D M1=5D M2=6D M3=7D  messages    S2S=8D  S2 scalar; 8D+2.. warm sinks
#define CS0 0
#define CS1 D
#define RS1 (2 * D)
#define RS2 (3 * D)
#define M0O (4 * D)
#define M1O (5 * D)
#define M2O (6 * D)
#define M3O (7 * D)
#define S2S (8 * D)
#define WRM (8 * D + 2)

// ---------------- K1: colsums of t0,t1 + op-array warming ----------------
// 2052 blocks x 256:
//   [0,512)     t0 colsum: 32-row stripe, col-quarter; atomics -> CS0 (128-way/addr)
//   [512,1024)  t1 colsum: same -> CS1
//   [1024,2048) unused range collapsed: grid is 1024+4; see below.
// Actual grid: 1028. Blocks [1024,1028) warm op0..op3 into L2/IC.
__global__ void __launch_bounds__(256) colsum_kernel(
        const float* __restrict__ t0, const float* __restrict__ t1,
        float* __restrict__ ws,
        const int* __restrict__ op0, const int* __restrict__ op1,
        const int* __restrict__ op2, const int* __restrict__ op3) {
    int b = blockIdx.x, tid = threadIdx.x;
    if (b < 1024) {
        const float* A = (b < 512) ? t0 : t1;
        float* out = ws + ((b < 512) ? CS0 : CS1);
        int lb = b & 511;
        int c4 = (lb & 3) * 256 + tid;             // fx4-column 0..1023
        int r0 = (lb >> 2) * 32;                   // 32-row stripe (128 stripes)
        const fx4* A4 = (const fx4*)A;
        fx4 s = (fx4){0.f, 0.f, 0.f, 0.f};
        #pragma unroll 8
        for (int r = 0; r < 32; ++r)
            s += A4[(size_t)(r0 + r) * (D / 4) + c4];
        atomicAdd(&out[c4 * 4 + 0], s.x);
        atomicAdd(&out[c4 * 4 + 1], s.y);
        atomicAdd(&out[c4 * 4 + 2], s.z);
        atomicAdd(&out[c4 * 4 + 3], s.w);
    } else {
        // warm one op array (2*D ints = 32 KB) into L2/IC
        const int* op = (b == 1024) ? op0 : (b == 1025) ? op1
                      : (b == 1026) ? op2 : op3;
        const ix4* o4 = (const ix4*)op;
        int acc = 0;
        #pragma unroll
        for (int j = 0; j < 8; ++j) {
            ix4 v = o4[tid + 256 * j];
            acc += v.x + v.y + v.z + v.w;
        }
        // keep the loads alive; sink is never read meaningfully
        if (tid == 0) ws[WRM + (b - 1024)] = (float)acc;
    }
}

// ---------------- single-block message kernels (R10-proven) ----------------

__device__ __forceinline__ float block_sum_1024(float v, float* red) {
    #pragma unroll
    for (int o = 32; o > 0; o >>= 1) v += __shfl_down(v, o);
    int lane = threadIdx.x & 63, wid = threadIdx.x >> 6;
    if (lane == 0) red[wid] = v;
    __syncthreads();
    if (threadIdx.x == 0) {
        float t = 0.f;
        #pragma unroll
        for (int w = 0; w < 16; ++w) t += red[w];
        red[0] = t;
    }
    __syncthreads();
    float r = red[0];
    __syncthreads();
    return r;
}

// msgsA: m0 = remap(CS0, op0); S0 = sum(m0); m1 = remap(CS1 + S0, op1)
__global__ void __launch_bounds__(1024) msgsA_kernel(
        float* __restrict__ ws, const int* __restrict__ op0,
        const int* __restrict__ op1) {
    __shared__ float m0[D], m1[D];
    __shared__ float red[16];
    int tid = threadIdx.x;

    int s0[4], d0[4], s1[4], d1[4];
    #pragma unroll
    for (int k = 0; k < 4; ++k) {
        int i = tid + k * 1024;
        s0[k] = op0[i]; d0[k] = op0[D + i];
        s1[k] = op1[i]; d1[k] = op1[D + i];
    }
    float g0[4], g1[4];
    #pragma unroll
    for (int k = 0; k < 4; ++k) {
        g0[k] = ws[CS0 + s0[k]];
        g1[k] = ws[CS1 + s1[k]];
    }
    #pragma unroll
    for (int k = 0; k < 4; ++k) {
        int i = tid + k * 1024;
        m0[i] = 0.f; m1[i] = 0.f;
    }
    __syncthreads();
    #pragma unroll
    for (int k = 0; k < 4; ++k) atomicAdd(&m0[d0[k]], g0[k]);
    __syncthreads();
    float p = 0.f;
    #pragma unroll
    for (int k = 0; k < 4; ++k) p += m0[tid + k * 1024];
    float S0 = block_sum_1024(p, red);
    #pragma unroll
    for (int k = 0; k < 4; ++k) atomicAdd(&m1[d1[k]], g1[k] + S0);
    __syncthreads();
    #pragma unroll
    for (int k = 0; k < 4; ++k) {
        int i = tid + k * 1024;
        ws[M0O + i] = m0[i];
        ws[M1O + i] = m1[i];
    }
}

// msgsB: m2 = remap(RS2 + 4095*m1, op2); S2 = sum(m2)
__global__ void __launch_bounds__(1024) msgsB_kernel(
        float* __restrict__ ws, const int* __restrict__ op2) {
    __shared__ float m2[D];
    __shared__ float red[16];
    int tid = threadIdx.x;

    int s2[4], d2[4];
    #pragma unroll
    for (int k = 0; k < 4; ++k) {
        int i = tid + k * 1024;
        s2[k] = op2[i]; d2[k] = op2[D + i];
    }
    float g2[4];
    #pragma unroll
    for (int k = 0; k < 4; ++k)
        g2[k] = ws[RS2 + s2[k]] + 4095.0f * ws[M1O + s2[k]];
    #pragma unroll
    for (int k = 0; k < 4; ++k) m2[tid + k * 1024] = 0.f;
    __syncthreads();
    #pragma unroll
    for (int k = 0; k < 4; ++k) atomicAdd(&m2[d2[k]], g2[k]);
    __syncthreads();
    float p = 0.f;
    #pragma unroll
    for (int k = 0; k < 4; ++k) p += m2[tid + k * 1024];
    float S2 = block_sum_1024(p, red);
    #pragma unroll
    for (int k = 0; k < 4; ++k) {
        int i = tid + k * 1024;
        ws[M2O + i] = m2[i];
    }
    if (tid == 0) ws[S2S] = S2;
}

// msgsC: m3 = remap(RS1 + 4095*m0 + S2, op3)
__global__ void __launch_bounds__(1024) msgsC_kernel(
        float* __restrict__ ws, const int* __restrict__ op3) {
    __shared__ float m3[D];
    int tid = threadIdx.x;

    int s3[4], d3[4];
    #pragma unroll
    for (int k = 0; k < 4; ++k) {
        int i = tid + k * 1024;
        s3[k] = op3[i]; d3[k] = op3[D + i];
    }
    float S2 = ws[S2S];
    float g3[4];
    #pragma unroll
    for (int k = 0; k < 4; ++k)
        g3[k] = ws[RS1 + s3[k]] + 4095.0f * ws[M0O + s3[k]] + S2;
    #pragma unroll
    for (int k = 0; k < 4; ++k) m3[tid + k * 1024] = 0.f;
    __syncthreads();
    #pragma unroll
    for (int k = 0; k < 4; ++k) atomicAdd(&m3[d3[k]], g3[k]);
    __syncthreads();
    #pragma unroll
    for (int k = 0; k < 4; ++k) {
        int i = tid + k * 1024;
        ws[M3O + i] = m3[i];
    }
}

// ---------------- apply kernels (R10-proven; 1 row per 256-thread block) ----------------

__device__ __forceinline__ void row_reduce_store(float s, float* dst) {
    __shared__ float red[4];
    #pragma unroll
    for (int o = 32; o > 0; o >>= 1) s += __shfl_down(s, o);
    int lane = threadIdx.x & 63, wid = threadIdx.x >> 6;
    if (lane == 0) red[wid] = s;
    __syncthreads();
    if (threadIdx.x == 0) *dst = (red[0] + red[1]) + (red[2] + red[3]);
}

// out2 = t2 + m1[row]; RS2[row] = rowsum(t2 row)
__global__ void __launch_bounds__(256) applyT2_kernel(
        const float* __restrict__ t2, float* __restrict__ ws,
        float* __restrict__ out2) {
    int row = blockIdx.x;
    size_t base = (size_t)row * D;
    const fx4* src = (const fx4*)(t2 + base);
    fx4* dst = (fx4*)(out2 + base);
    float rr = ws[M1O + row];

    fx4 v[4];
    float s = 0.f;
    #pragma unroll
    for (int k = 0; k < 4; ++k) {
        v[k] = src[threadIdx.x + 256 * k];
        s += (v[k].x + v[k].y) + (v[k].z + v[k].w);
    }
    #pragma unroll
    for (int k = 0; k < 4; ++k)
        __builtin_nontemporal_store(v[k] + rr, &dst[threadIdx.x + 256 * k]);
    row_reduce_store(s, ws + RS2 + row);
}

// out1 = t1 + m0[row] + m2[col]; RS1[row] = rowsum(t1 row)
__global__ void __launch_bounds__(256) applyT1_kernel(
        const float* __restrict__ t1, float* __restrict__ ws,
        float* __restrict__ out1) {
    int row = blockIdx.x;
    size_t base = (size_t)row * D;
    const fx4* src = (const fx4*)(t1 + base);
    const fx4* c4 = (const fx4*)(ws + M2O);
    fx4* dst = (fx4*)(out1 + base);
    float rr = ws[M0O + row];

    fx4 v[4], c[4];
    float s = 0.f;
    #pragma unroll
    for (int k = 0; k < 4; ++k) {
        v[k] = src[threadIdx.x + 256 * k];
        c[k] = c4[threadIdx.x + 256 * k];
        s += (v[k].x + v[k].y) + (v[k].z + v[k].w);
    }
    #pragma unroll
    for (int k = 0; k < 4; ++k)
        __builtin_nontemporal_store(v[k] + c[k] + rr,
                                    &dst[threadIdx.x + 256 * k]);
    row_reduce_store(s, ws + RS1 + row);
}

// out0 = t0 + m3[col]
__global__ void __launch_bounds__(256) applyT0_kernel(
        const float* __restrict__ t0, const float* __restrict__ ws,
        float* __restrict__ out0) {
    int row = blockIdx.x;
    size_t base = (size_t)row * D;
    const fx4* src = (const fx4*)(t0 + base);
    const fx4* c4 = (const fx4*)(ws + M3O);
    fx4* dst = (fx4*)(out0 + base);

    #pragma unroll
    for (int k = 0; k < 4; ++k) {
        fx4 r = src[threadIdx.x + 256 * k] + c4[threadIdx.x + 256 * k];
        __builtin_nontemporal_store(r, &dst[threadIdx.x + 256 * k]);
    }
}

extern "C" void kernel_launch(void* const* d_in, const int* in_sizes, int n_in,
                              void* d_out, int out_size, void* d_ws, size_t ws_size,
                              hipStream_t stream) {
    const float* t0 = (const float*)d_in[0];
    const float* t1 = (const float*)d_in[1];
    const float* t2 = (const float*)d_in[2];
    const int* op0 = (const int*)d_in[3];
    const int* op1 = (const int*)d_in[4];
    const int* op2 = (const int*)d_in[5];
    const int* op3 = (const int*)d_in[6];
    float* out = (float*)d_out;
    float* ws = (float*)d_ws;

    hipMemsetAsync(ws, 0, 2 * D * sizeof(float), stream);     // CS0, CS1

    colsum_kernel<<<1028, 256, 0, stream>>>(t0, t1, ws, op0, op1, op2, op3);
    msgsA_kernel<<<1, 1024, 0, stream>>>(ws, op0, op1);       // m0, m1
    applyT2_kernel<<<D, 256, 0, stream>>>(t2, ws, out + 2 * (size_t)D * D);
    msgsB_kernel<<<1, 1024, 0, stream>>>(ws, op2);            // m2, S2
    applyT1_kernel<<<D, 256, 0, stream>>>(t1, ws, out + 1 * (size_t)D * D);
    msgsC_kernel<<<1, 1024, 0, stream>>>(ws, op3);            // m3
    applyT0_kernel<<<D, 256, 0, stream>>>(t0, ws, out + 0 * (size_t)D * D);
}

// Round 13
// 140.563 us; speedup vs baseline: 1.3589x; 1.0287x over previous
//
#include <hip/hip_runtime.h>

#define D 4096

typedef float fx4 __attribute__((ext_vector_type(4)));

// ws layout (floats):
//   CS0=0 colsum0[D] (atomics; memset)   CS1=D colsum1[D] (atomics; memset)
//   RS1=2D rowsum1[D] (pass 1)           RS2=3D rowsum2[D] (fused in applyT2)
//   M0=4D M1=5D M2=6D M3=7D messages
#define CS0 0
#define CS1 D
#define RS1 (2 * D)
#define RS2 (3 * D)
#define M0O (4 * D)
#define M1O (5 * D)
#define M2O (6 * D)
#define M3O (7 * D)

// ---------------- K1: colsum t0,t1 + rowsum t1 (R3-proven geometry) ----------------
// 1536 blocks x 256:
//   [0,256)     colsum t0 -> atomics CS0 (64-row stripes, 64-way/addr)
//   [256,512)   colsum t1 -> atomics CS1
//   [512,1536)  rowsum t1 -> RS1 (concurrent with colsum t1; re-read L2/IC-hits)
__global__ void __launch_bounds__(256) reduce_kernel(
        const float* __restrict__ t0, const float* __restrict__ t1,
        float* __restrict__ ws) {
    int b = blockIdx.x;
    if (b < 512) {
        const float* A = (b < 256) ? t0 : t1;
        float* out = ws + ((b < 256) ? CS0 : CS1);
        int lb = b & 255;
        int c4 = (lb & 3) * 256 + threadIdx.x;     // fx4-column 0..1023
        int r0 = (lb >> 2) * 64;                   // 64-row stripe
        const fx4* A4 = (const fx4*)A;
        fx4 s = (fx4){0.f, 0.f, 0.f, 0.f};
        #pragma unroll 8
        for (int r = 0; r < 64; ++r)
            s += A4[(size_t)(r0 + r) * (D / 4) + c4];
        atomicAdd(&out[c4 * 4 + 0], s.x);
        atomicAdd(&out[c4 * 4 + 1], s.y);
        atomicAdd(&out[c4 * 4 + 2], s.z);
        atomicAdd(&out[c4 * 4 + 3], s.w);
    } else {
        int lb = b - 512;                          // 0..1023
        int wid = threadIdx.x >> 6, lane = threadIdx.x & 63;
        int row = lb * 4 + wid;
        const fx4* R = (const fx4*)(t1 + (size_t)row * D);
        float s = 0.f;
        #pragma unroll
        for (int j = 0; j < 16; ++j) {
            fx4 v = R[lane + 64 * j];
            s += (v.x + v.y) + (v.z + v.w);
        }
        #pragma unroll
        for (int o = 32; o > 0; o >>= 1) s += __shfl_down(s, o);
        if (lane == 0) ws[RS1 + row] = s;
    }
}

// ---------------- single-block message kernels ----------------

__device__ __forceinline__ float block_sum_1024(float v, float* red) {
    #pragma unroll
    for (int o = 32; o > 0; o >>= 1) v += __shfl_down(v, o);
    int lane = threadIdx.x & 63, wid = threadIdx.x >> 6;
    if (lane == 0) red[wid] = v;
    __syncthreads();
    if (threadIdx.x == 0) {
        float t = 0.f;
        #pragma unroll
        for (int w = 0; w < 16; ++w) t += red[w];
        red[0] = t;
    }
    __syncthreads();
    float r = red[0];
    __syncthreads();
    return r;
}

// msgsA: m0 = remap(CS0, op0); S0 = sum(m0); m1 = remap(CS1 + S0, op1)  [R10-proven]
__global__ void __launch_bounds__(1024) msgsA_kernel(
        float* __restrict__ ws, const int* __restrict__ op0,
        const int* __restrict__ op1) {
    __shared__ float m0[D], m1[D];
    __shared__ float red[16];
    int tid = threadIdx.x;

    int s0[4], d0[4], s1[4], d1[4];
    #pragma unroll
    for (int k = 0; k < 4; ++k) {
        int i = tid + k * 1024;
        s0[k] = op0[i]; d0[k] = op0[D + i];
        s1[k] = op1[i]; d1[k] = op1[D + i];
    }
    float g0[4], g1[4];
    #pragma unroll
    for (int k = 0; k < 4; ++k) {
        g0[k] = ws[CS0 + s0[k]];
        g1[k] = ws[CS1 + s1[k]];
    }
    #pragma unroll
    for (int k = 0; k < 4; ++k) {
        int i = tid + k * 1024;
        m0[i] = 0.f; m1[i] = 0.f;
    }
    __syncthreads();
    #pragma unroll
    for (int k = 0; k < 4; ++k) atomicAdd(&m0[d0[k]], g0[k]);
    __syncthreads();
    float p = 0.f;
    #pragma unroll
    for (int k = 0; k < 4; ++k) p += m0[tid + k * 1024];
    float S0 = block_sum_1024(p, red);
    #pragma unroll
    for (int k = 0; k < 4; ++k) atomicAdd(&m1[d1[k]], g1[k] + S0);
    __syncthreads();
    #pragma unroll
    for (int k = 0; k < 4; ++k) {
        int i = tid + k * 1024;
        ws[M0O + i] = m0[i];
        ws[M1O + i] = m1[i];
    }
}

// msgsBC: m2 = remap(RS2 + 4095*m1, op2); S2 = sum(m2);
//         m3 = remap(RS1 + 4095*m0 + S2, op3)
__global__ void __launch_bounds__(1024) msgsBC_kernel(
        float* __restrict__ ws, const int* __restrict__ op2,
        const int* __restrict__ op3) {
    __shared__ float m2[D], m3[D];
    __shared__ float red[16];
    int tid = threadIdx.x;

    // phase B indices + gathers
    int s2[4], d2[4], s3[4], d3[4];
    #pragma unroll
    for (int k = 0; k < 4; ++k) {
        int i = tid + k * 1024;
        s2[k] = op2[i]; d2[k] = op2[D + i];
        s3[k] = op3[i]; d3[k] = op3[D + i];
    }
    float g2[4], g3p[4];
    #pragma unroll
    for (int k = 0; k < 4; ++k) {
        g2[k]  = ws[RS2 + s2[k]] + 4095.0f * ws[M1O + s2[k]];
        g3p[k] = ws[RS1 + s3[k]] + 4095.0f * ws[M0O + s3[k]];   // + S2 later
    }
    #pragma unroll
    for (int k = 0; k < 4; ++k) {
        int i = tid + k * 1024;
        m2[i] = 0.f; m3[i] = 0.f;
    }
    __syncthreads();
    #pragma unroll
    for (int k = 0; k < 4; ++k) atomicAdd(&m2[d2[k]], g2[k]);
    __syncthreads();
    float p = 0.f;
    #pragma unroll
    for (int k = 0; k < 4; ++k) p += m2[tid + k * 1024];
    float S2 = block_sum_1024(p, red);
    #pragma unroll
    for (int k = 0; k < 4; ++k) atomicAdd(&m3[d3[k]], g3p[k] + S2);
    __syncthreads();
    #pragma unroll
    for (int k = 0; k < 4; ++k) {
        int i = tid + k * 1024;
        ws[M2O + i] = m2[i];
        ws[M3O + i] = m3[i];
    }
}

// ---------------- apply kernels (1 row per 256-thread block) ----------------

__device__ __forceinline__ void row_reduce_store(float s, float* dst) {
    __shared__ float red[4];
    #pragma unroll
    for (int o = 32; o > 0; o >>= 1) s += __shfl_down(s, o);
    int lane = threadIdx.x & 63, wid = threadIdx.x >> 6;
    if (lane == 0) red[wid] = s;
    __syncthreads();
    if (threadIdx.x == 0) *dst = (red[0] + red[1]) + (red[2] + red[3]);
}

// out2 = t2 + m1[row]; RS2[row] = rowsum(t2 row)   [R10-proven]
__global__ void __launch_bounds__(256) applyT2_kernel(
        const float* __restrict__ t2, float* __restrict__ ws,
        float* __restrict__ out2) {
    int row = blockIdx.x;
    size_t base = (size_t)row * D;
    const fx4* src = (const fx4*)(t2 + base);
    fx4* dst = (fx4*)(out2 + base);
    float rr = ws[M1O + row];

    fx4 v[4];
    float s = 0.f;
    #pragma unroll
    for (int k = 0; k < 4; ++k) {
        v[k] = src[threadIdx.x + 256 * k];
        s += (v[k].x + v[k].y) + (v[k].z + v[k].w);
    }
    #pragma unroll
    for (int k = 0; k < 4; ++k)
        __builtin_nontemporal_store(v[k] + rr, &dst[threadIdx.x + 256 * k]);
    row_reduce_store(s, ws + RS2 + row);
}

// out1 = t1 + m0[row] + m2[col]   (no fused rowsum; RS1 came from pass 1)
__global__ void __launch_bounds__(256) applyT1_kernel(
        const float* __restrict__ t1, const float* __restrict__ ws,
        float* __restrict__ out1) {
    int row = blockIdx.x;
    size_t base = (size_t)row * D;
    const fx4* src = (const fx4*)(t1 + base);
    const fx4* c4 = (const fx4*)(ws + M2O);
    fx4* dst = (fx4*)(out1 + base);
    float rr = ws[M0O + row];

    #pragma unroll
    for (int k = 0; k < 4; ++k) {
        fx4 r = src[threadIdx.x + 256 * k] + c4[threadIdx.x + 256 * k] + rr;
        __builtin_nontemporal_store(r, &dst[threadIdx.x + 256 * k]);
    }
}

// out0 = t0 + m3[col]   [R10-proven]
__global__ void __launch_bounds__(256) applyT0_kernel(
        const float* __restrict__ t0, const float* __restrict__ ws,
        float* __restrict__ out0) {
    int row = blockIdx.x;
    size_t base = (size_t)row * D;
    const fx4* src = (const fx4*)(t0 + base);
    const fx4* c4 = (const fx4*)(ws + M3O);
    fx4* dst = (fx4*)(out0 + base);

    #pragma unroll
    for (int k = 0; k < 4; ++k) {
        fx4 r = src[threadIdx.x + 256 * k] + c4[threadIdx.x + 256 * k];
        __builtin_nontemporal_store(r, &dst[threadIdx.x + 256 * k]);
    }
}

extern "C" void kernel_launch(void* const* d_in, const int* in_sizes, int n_in,
                              void* d_out, int out_size, void* d_ws, size_t ws_size,
                              hipStream_t stream) {
    const float* t0 = (const float*)d_in[0];
    const float* t1 = (const float*)d_in[1];
    const float* t2 = (const float*)d_in[2];
    const int* op0 = (const int*)d_in[3];
    const int* op1 = (const int*)d_in[4];
    const int* op2 = (const int*)d_in[5];
    const int* op3 = (const int*)d_in[6];
    float* out = (float*)d_out;
    float* ws = (float*)d_ws;

    hipMemsetAsync(ws, 0, 2 * D * sizeof(float), stream);     // CS0, CS1

    reduce_kernel<<<1536, 256, 0, stream>>>(t0, t1, ws);      // colsums + rowsum1
    msgsA_kernel<<<1, 1024, 0, stream>>>(ws, op0, op1);       // m0, m1
    applyT2_kernel<<<D, 256, 0, stream>>>(t2, ws, out + 2 * (size_t)D * D);  // +RS2
    msgsBC_kernel<<<1, 1024, 0, stream>>>(ws, op2, op3);      // m2, S2, m3
    applyT1_kernel<<<D, 256, 0, stream>>>(t1, ws, out + 1 * (size_t)D * D);
    applyT0_kernel<<<D, 256, 0, stream>>>(t0, ws, out + 0 * (size_t)D * D);
}